// Round 12
// baseline (368.585 us; speedup 1.0000x reference)
//
#include <hip/hip_runtime.h>
#include <math.h>

// ---------------------------------------------------------------------------
// ViT forward, f32. B=1024, D=1024, H=16, DH=64, S=50, OUT=1000.
// Class-token attention collapsed to 16-dim patch algebra (rounds 10-11).
// Round-12: k_fused coalesced (d = i*64+lane) + Phase E split into k_av
// (per-head LDS mini-GEMM); GEMMs upgraded to 128x128 tile / 8x8 microtile.
// ---------------------------------------------------------------------------

#define EPS 1e-5f

__device__ __forceinline__ float warp_sum64(float v) {
    #pragma unroll
    for (int off = 32; off >= 1; off >>= 1) v += __shfl_xor(v, off, 64);
    return v;
}
__device__ __forceinline__ float warp_max64(float v) {
    #pragma unroll
    for (int off = 32; off >= 1; off >>= 1) v = fmaxf(v, __shfl_xor(v, off, 64));
    return v;
}

__device__ __forceinline__ float block_sum(float v, float* red) {
    v = warp_sum64(v);
    int lane = threadIdx.x & 63, w = threadIdx.x >> 6;
    if (lane == 0) red[w] = v;
    __syncthreads();
    int nw = blockDim.x >> 6;
    if (w == 0) {
        float x = (lane < nw) ? red[lane] : 0.f;
        x = warp_sum64(x);
        if (lane == 0) red[0] = x;
    }
    __syncthreads();
    float r = red[0];
    __syncthreads();
    return r;
}

__device__ __forceinline__ float block_max(float v, float* red) {
    v = warp_max64(v);
    int lane = threadIdx.x & 63, w = threadIdx.x >> 6;
    if (lane == 0) red[w] = v;
    __syncthreads();
    int nw = blockDim.x >> 6;
    if (w == 0) {
        float x = (lane < nw) ? red[lane] : -INFINITY;
        x = warp_max64(x);
        if (lane == 0) red[0] = x;
    }
    __syncthreads();
    float r = red[0];
    __syncthreads();
    return r;
}

// ---------------------------------------------------------------------------
// PE table
// ---------------------------------------------------------------------------
__global__ __launch_bounds__(256) void k_pe(float* __restrict__ pe) {
    int s = blockIdx.x;
    for (int d = threadIdx.x; d < 1024; d += 256) {
        int di = d & ~1;
        float freq = expf(-((float)di * (1.0f / 1024.f)) * 9.210340371976184f);
        float arg = (float)s * freq;
        pe[s * 1024 + d] = (d & 1) ? cosf(arg) : sinf(arg);
    }
}

// ---------------------------------------------------------------------------
// Prep A (1 block): tok0c=cls+pe0, LN1 -> n0; q0 = Wq n0 + bq;
// qk[d] = 32 * sum_e Wk[h][e][dl] q0[e]  (sqrt(D) temperature);
// qlw = qk*ln1w; score0[h]=qk.n0, kappa[h]=sum qlw, beta[h]=qk.lb per head.
// ---------------------------------------------------------------------------
__global__ __launch_bounds__(256) void k_prep_a(
    const float* __restrict__ cls, const float* __restrict__ pe,
    const float* __restrict__ ln1w, const float* __restrict__ ln1b,
    const float* __restrict__ Wq, const float* __restrict__ bq,
    const float* __restrict__ Wk,
    float* __restrict__ tok0c, float* __restrict__ n0g,
    float* __restrict__ qlw,
    float* __restrict__ score0, float* __restrict__ kap, float* __restrict__ bet)
{
    __shared__ float red[8];
    __shared__ float n0s[1024], q0s[1024];
    __shared__ float partA[256], partK[256], partB[256];
    int t = threadIdx.x;
    int h = t >> 4;

    float tv[4];
    #pragma unroll
    for (int i = 0; i < 4; ++i) {
        int d = t * 4 + i;
        tv[i] = cls[d] + pe[d];
        tok0c[d] = tv[i];
    }
    float sum = block_sum(tv[0] + tv[1] + tv[2] + tv[3], red);
    float mu = sum * (1.f / 1024.f);
    float d2 = 0.f;
    #pragma unroll
    for (int i = 0; i < 4; ++i) { float dv = tv[i] - mu; d2 = fmaf(dv, dv, d2); }
    float var = block_sum(d2, red) * (1.f / 1024.f);
    float rstd = rsqrtf(var + EPS);
    #pragma unroll
    for (int i = 0; i < 4; ++i) {
        int d = t * 4 + i;
        float nv = (tv[i] - mu) * rstd * ln1w[d] + ln1b[d];
        n0s[d] = nv; n0g[d] = nv;
    }
    __syncthreads();

    #pragma unroll
    for (int i = 0; i < 4; ++i) {
        int e = t * 4 + i, el = e & 63;
        const float* wr = Wq + ((size_t)h << 12) + el * 64;
        float acc = bq[e];
        for (int dd = 0; dd < 64; ++dd) acc = fmaf(wr[dd], n0s[(h << 6) + dd], acc);
        q0s[e] = acc;
    }
    __syncthreads();

    float pA = 0.f, pK = 0.f, pB = 0.f;
    #pragma unroll
    for (int i = 0; i < 4; ++i) {
        int d = t * 4 + i, dl = d & 63;
        const float* wc = Wk + ((size_t)h << 12) + dl;
        float acc = 0.f;
        for (int ee = 0; ee < 64; ++ee) acc = fmaf(wc[ee * 64], q0s[(h << 6) + ee], acc);
        acc *= 32.0f;                  // sqrt(D)=32 temperature
        float ql = acc * ln1w[d];
        qlw[d] = ql;
        pA = fmaf(acc, n0s[d], pA);
        pK += ql;
        pB = fmaf(acc, ln1b[d], pB);
    }
    partA[t] = pA; partK[t] = pK; partB[t] = pB;
    __syncthreads();
    if (t < 16) {
        float sA = 0.f, sK = 0.f, sB = 0.f;
        #pragma unroll
        for (int i = 0; i < 16; ++i) {
            sA += partA[t * 16 + i]; sK += partK[t * 16 + i]; sB += partB[t * 16 + i];
        }
        score0[t] = sA; kap[t] = sK; bet[t] = sB;
    }
}

// ---------------------------------------------------------------------------
// Prep B (52 blocks): 0..49 -> pw[s][16], pe2[s], pemean[s], pesum[s][16];
// 50 -> G=Wp^T Wp, u; 51 -> g[h][16].
// ---------------------------------------------------------------------------
__global__ __launch_bounds__(256) void k_prep_b(
    const float* __restrict__ pe, const float* __restrict__ Wp,
    const float* __restrict__ qlw,
    float* __restrict__ pwt, float* __restrict__ pe2t,
    float* __restrict__ pemean, float* __restrict__ pesum,
    float* __restrict__ Gt, float* __restrict__ ut, float* __restrict__ gt)
{
    int blk = blockIdx.x, t = threadIdx.x;
    if (blk < 50) {
        __shared__ float red[8];
        __shared__ float pwbuf[256 * 16];
        __shared__ float psbuf[256];
        int s = blk;
        float pwp[16];
        #pragma unroll
        for (int j = 0; j < 16; ++j) pwp[j] = 0.f;
        float pep = 0.f, pe2p = 0.f, psp = 0.f;
        #pragma unroll
        for (int i = 0; i < 4; ++i) {
            int d = t * 4 + i;
            float e = pe[s * 1024 + d];
            pep += e; pe2p = fmaf(e, e, pe2p); psp = fmaf(qlw[d], e, psp);
            const float* wr = Wp + (size_t)d * 16;
            #pragma unroll
            for (int j = 0; j < 16; ++j) pwp[j] = fmaf(wr[j], e, pwp[j]);
        }
        #pragma unroll
        for (int j = 0; j < 16; ++j) pwbuf[t * 16 + j] = pwp[j];
        psbuf[t] = psp;
        float pes = block_sum(pep, red);
        float pe2s = block_sum(pe2p, red);
        if (t < 16) {
            float a = 0.f;
            for (int k = 0; k < 256; ++k) a += pwbuf[k * 16 + t];
            pwt[s * 16 + t] = a;
            float b = 0.f;
            #pragma unroll
            for (int k = 0; k < 16; ++k) b += psbuf[t * 16 + k];
            pesum[s * 16 + t] = b;
        }
        if (t == 0) { pe2t[s] = pe2s; pemean[s] = pes * (1.f / 1024.f); }
    } else if (blk == 50) {
        int j = t >> 4, k = t & 15;
        float a = 0.f;
        for (int d = 0; d < 1024; ++d)
            a = fmaf(Wp[(size_t)d * 16 + j], Wp[(size_t)d * 16 + k], a);
        Gt[j * 16 + k] = a;
        if (t < 16) {
            float ua = 0.f;
            for (int d = 0; d < 1024; ++d) ua += Wp[(size_t)d * 16 + t];
            ut[t] = ua * (1.f / 1024.f);
        }
    } else {
        int h = t >> 4, j = t & 15;
        float a = 0.f;
        for (int dl = 0; dl < 64; ++dl) {
            int d = h * 64 + dl;
            a = fmaf(qlw[d], Wp[(size_t)d * 16 + j], a);
        }
        gt[h * 16 + j] = a;
    }
}

// ---------------------------------------------------------------------------
// Fused embed+attention -> context c. One wave per batch (4 waves/block).
// Phase A (lane=s): stats+scores. B: softmax. C: wpatch/wmu. D: c (coalesced,
// d = i*64+lane so head=i is wave-uniform; pe/n0/lw/lb reads + c writes all
// stride-1 across lanes). A0 = Wv c + bv moved to k_av.
// ---------------------------------------------------------------------------
__global__ __launch_bounds__(256) void k_fused(
    const float* __restrict__ x, const float* __restrict__ pe,
    const float* __restrict__ Wp,
    const float* __restrict__ ln1w, const float* __restrict__ ln1b,
    const float* __restrict__ n0g, const float* __restrict__ score0,
    const float* __restrict__ kap, const float* __restrict__ bet,
    const float* __restrict__ Gt, const float* __restrict__ ut,
    const float* __restrict__ gt,
    const float* __restrict__ pwt, const float* __restrict__ pe2t,
    const float* __restrict__ pemean, const float* __restrict__ pesum,
    float* __restrict__ cg)
{
    __shared__ float Gs[256], gs[256];
    __shared__ float us[16], kaps[16], bets[16], s0s[16];
    __shared__ int   prc[50];
    __shared__ float n0s[1024], lws[1024], lbs[1024];
    __shared__ float xs[4][800];
    __shared__ float mus[4][52], rss[4][52];
    __shared__ float sc[4][16][52];
    __shared__ float wpat[4][16][17];
    __shared__ float wmus[4][16];

    int t = threadIdx.x, w = t >> 6, lane = t & 63;
    int b = blockIdx.x * 4 + w;

    Gs[t] = Gt[t];
    gs[t] = gt[t];
    if (t < 16) { us[t] = ut[t]; kaps[t] = kap[t]; bets[t] = bet[t]; s0s[t] = score0[t]; }
    if (t >= 1 && t < 50) prc[t] = ((t - 1) / 7) * 112 + ((t - 1) % 7) * 4;
    #pragma unroll
    for (int i = 0; i < 4; ++i) {
        int d = t + (i << 8);
        n0s[d] = n0g[d]; lws[d] = ln1w[d]; lbs[d] = ln1b[d];
    }
    for (int i = lane; i < 784; i += 64) xs[w][i] = x[b * 784 + i];
    __syncthreads();

    // ---- Phase A: per-row stats + scores (lane = s) ----
    {
        int s = lane;
        if (s >= 1 && s < 50) {
            float p[16];
            int off = prc[s];
            #pragma unroll
            for (int j = 0; j < 16; ++j) p[j] = xs[w][off + (j >> 2) * 28 + (j & 3)];
            float mu = pemean[s];
            #pragma unroll
            for (int j = 0; j < 16; ++j) mu = fmaf(us[j], p[j], mu);
            float ssq = pe2t[s];
            #pragma unroll
            for (int j = 0; j < 16; ++j) {
                float gpj = 0.f;
                #pragma unroll
                for (int k = 0; k < 16; ++k) gpj = fmaf(Gs[j * 16 + k], p[k], gpj);
                ssq = fmaf(p[j], gpj, ssq);
            }
            const float* pwr = pwt + s * 16;
            #pragma unroll
            for (int j = 0; j < 16; ++j) ssq = fmaf(2.f * p[j], pwr[j], ssq);
            float var = ssq * (1.f / 1024.f) - mu * mu;
            float rsv = rsqrtf(var + EPS);
            mus[w][s] = mu; rss[w][s] = rsv;
            const float* pss = pesum + s * 16;
            #pragma unroll
            for (int h = 0; h < 16; ++h) {
                float gp = 0.f;
                #pragma unroll
                for (int j = 0; j < 16; ++j) gp = fmaf(gs[h * 16 + j], p[j], gp);
                sc[w][h][s] = rsv * (gp + pss[h] - mu * kaps[h]) + bets[h];
            }
        } else if (s == 50) {
            #pragma unroll
            for (int h = 0; h < 16; ++h) sc[w][h][0] = s0s[h];
        }
    }
    __syncthreads();

    // ---- Phase B: softmax over 50 per head (4 lanes per head) ----
    int h = lane & 15, q = lane >> 4;
    {
        int sb = q * 13, se = (sb + 13 < 50) ? sb + 13 : 50;
        float mx = -1e30f;
        for (int ss = sb; ss < se; ++ss) mx = fmaxf(mx, sc[w][h][ss]);
        mx = fmaxf(mx, __shfl_xor(mx, 16, 64));
        mx = fmaxf(mx, __shfl_xor(mx, 32, 64));
        float sm = 0.f;
        for (int ss = sb; ss < se; ++ss) {
            float e = expf(sc[w][h][ss] - mx);
            sc[w][h][ss] = e;
            sm += e;
        }
        sm += __shfl_xor(sm, 16, 64);
        sm += __shfl_xor(sm, 32, 64);
        float inv = 1.f / sm;
        for (int ss = sb; ss < se; ++ss) sc[w][h][ss] *= inv;
    }
    __syncthreads();

    // ---- Phase C: wpatch_h[16], wmu_h ----
    {
        int sb = q * 13, se = (sb + 13 < 50) ? sb + 13 : 50;
        int s0c = (q == 0) ? 1 : sb;
        float acc[16], amu = 0.f;
        #pragma unroll
        for (int j = 0; j < 16; ++j) acc[j] = 0.f;
        for (int ss = s0c; ss < se; ++ss) {
            float wgt = sc[w][h][ss] * rss[w][ss];
            int off = prc[ss];
            #pragma unroll
            for (int j = 0; j < 16; ++j)
                acc[j] = fmaf(wgt, xs[w][off + (j >> 2) * 28 + (j & 3)], acc[j]);
            amu = fmaf(wgt, mus[w][ss], amu);
        }
        #pragma unroll
        for (int j = 0; j < 16; ++j) {
            acc[j] += __shfl_xor(acc[j], 16, 64);
            acc[j] += __shfl_xor(acc[j], 32, 64);
        }
        amu += __shfl_xor(amu, 16, 64);
        amu += __shfl_xor(amu, 32, 64);
        if (q == 0) {
            #pragma unroll
            for (int j = 0; j < 16; ++j) wpat[w][h][j] = acc[j];
            wmus[w][h] = amu;
        }
    }
    __syncthreads();

    // ---- Phase D: context c, coalesced: d = i*64 + lane, head = i ----
    {
        float wpe[16];
        #pragma unroll
        for (int i = 0; i < 16; ++i) wpe[i] = 0.f;
        for (int ss = 1; ss < 50; ++ss) {
            float rsv = rss[w][ss];
            const float* per = pe + ss * 1024 + lane;
            #pragma unroll
            for (int i = 0; i < 16; ++i) {
                float wgt = sc[w][i][ss] * rsv;         // LDS broadcast
                wpe[i] = fmaf(wgt, per[i * 64], wpe[i]); // coalesced dword
            }
        }
        #pragma unroll
        for (int i = 0; i < 16; ++i) {
            int d = i * 64 + lane;
            float p0 = sc[w][i][0];
            const float4* wr = (const float4*)(Wp + (size_t)d * 16);
            float4 wa = wr[0], wb = wr[1], wc = wr[2], wd = wr[3];
            const float* wp_h = wpat[w][i];              // wave-uniform
            float wp_ = 0.f;
            wp_ = fmaf(wa.x, wp_h[0], wp_);  wp_ = fmaf(wa.y, wp_h[1], wp_);
            wp_ = fmaf(wa.z, wp_h[2], wp_);  wp_ = fmaf(wa.w, wp_h[3], wp_);
            wp_ = fmaf(wb.x, wp_h[4], wp_);  wp_ = fmaf(wb.y, wp_h[5], wp_);
            wp_ = fmaf(wb.z, wp_h[6], wp_);  wp_ = fmaf(wb.w, wp_h[7], wp_);
            wp_ = fmaf(wc.x, wp_h[8], wp_);  wp_ = fmaf(wc.y, wp_h[9], wp_);
            wp_ = fmaf(wc.z, wp_h[10], wp_); wp_ = fmaf(wc.w, wp_h[11], wp_);
            wp_ = fmaf(wd.x, wp_h[12], wp_); wp_ = fmaf(wd.y, wp_h[13], wp_);
            wp_ = fmaf(wd.z, wp_h[14], wp_); wp_ = fmaf(wd.w, wp_h[15], wp_);
            float ci = p0 * n0s[d] + lws[d] * (wp_ + wpe[i] - wmus[w][i])
                     + lbs[d] * (1.f - p0);
            cg[(size_t)b * 1024 + d] = ci;               // coalesced dword
        }
    }
}

// ---------------------------------------------------------------------------
// k_av: A0[b, h*64+e] = sum_d Wv[h][e][d] * c[b, h*64+d] + bv[h*64+e].
// Block = (btile of 64, head). Wv[h] and c-tile staged transposed in LDS.
// ---------------------------------------------------------------------------
__global__ __launch_bounds__(256) void k_av(
    const float* __restrict__ cg, const float* __restrict__ Wv,
    const float* __restrict__ bv, float* __restrict__ A0)
{
    __shared__ __align__(16) float wvt[64 * 68];   // [d][e]
    __shared__ __align__(16) float cst[64 * 68];   // [d][bb]
    int b0 = blockIdx.x * 64, hh = blockIdx.y;
    int tid = threadIdx.x;

    for (int idx = tid; idx < 4096; idx += 256) {
        int row = idx >> 6, col = idx & 63;        // Wv: row=e, col=d; c: row=bb, col=d
        wvt[col * 68 + row] = Wv[((size_t)hh << 12) + idx];
        cst[col * 68 + row] = cg[(size_t)(b0 + row) * 1024 + (hh << 6) + col];
    }
    __syncthreads();

    int bt = (tid & 15) * 4, et = (tid >> 4) * 4;
    float acc[4][4] = {{0.f}};
    #pragma unroll 8
    for (int d = 0; d < 64; ++d) {
        float4 cv = *(const float4*)&cst[d * 68 + bt];
        float4 wv4 = *(const float4*)&wvt[d * 68 + et];
        acc[0][0] = fmaf(cv.x, wv4.x, acc[0][0]);
        acc[0][1] = fmaf(cv.x, wv4.y, acc[0][1]);
        acc[0][2] = fmaf(cv.x, wv4.z, acc[0][2]);
        acc[0][3] = fmaf(cv.x, wv4.w, acc[0][3]);
        acc[1][0] = fmaf(cv.y, wv4.x, acc[1][0]);
        acc[1][1] = fmaf(cv.y, wv4.y, acc[1][1]);
        acc[1][2] = fmaf(cv.y, wv4.z, acc[1][2]);
        acc[1][3] = fmaf(cv.y, wv4.w, acc[1][3]);
        acc[2][0] = fmaf(cv.z, wv4.x, acc[2][0]);
        acc[2][1] = fmaf(cv.z, wv4.y, acc[2][1]);
        acc[2][2] = fmaf(cv.z, wv4.z, acc[2][2]);
        acc[2][3] = fmaf(cv.z, wv4.w, acc[2][3]);
        acc[3][0] = fmaf(cv.w, wv4.x, acc[3][0]);
        acc[3][1] = fmaf(cv.w, wv4.y, acc[3][1]);
        acc[3][2] = fmaf(cv.w, wv4.z, acc[3][2]);
        acc[3][3] = fmaf(cv.w, wv4.w, acc[3][3]);
    }
    #pragma unroll
    for (int i = 0; i < 4; ++i) {
        int b = b0 + bt + i;
        #pragma unroll
        for (int j = 0; j < 4; ++j) {
            int e = (hh << 6) + et + j;
            A0[(size_t)b * 1024 + e] = acc[i][j] + bv[e];
        }
    }
}

// ---------------------------------------------------------------------------
// C1: t = tok0c + A0; tok0[b]=t; LN2 -> n2. One block per b.
// ---------------------------------------------------------------------------
__global__ __launch_bounds__(256) void k_c1(
    const float* __restrict__ tok0c, const float* __restrict__ A0,
    const float* __restrict__ w2, const float* __restrict__ b2,
    float* __restrict__ tok0, float* __restrict__ n2)
{
    int b = blockIdx.x, tid = threadIdx.x;
    __shared__ float red[8];
    float t[4];
    #pragma unroll
    for (int i = 0; i < 4; ++i) {
        int d = tid + (i << 8);
        t[i] = tok0c[d] + A0[(size_t)b * 1024 + d];
    }
    float sum = block_sum(t[0] + t[1] + t[2] + t[3], red);
    float mu = sum * (1.f / 1024.f);
    float d2 = 0.f;
    #pragma unroll
    for (int i = 0; i < 4; ++i) { float dv = t[i] - mu; d2 = fmaf(dv, dv, d2); }
    float var = block_sum(d2, red) * (1.f / 1024.f);
    float rstd = rsqrtf(var + EPS);
    #pragma unroll
    for (int i = 0; i < 4; ++i) {
        int d = tid + (i << 8);
        tok0[(size_t)b * 1024 + d] = t[i];
        n2[(size_t)b * 1024 + d] = (t[i] - mu) * rstd * w2[d] + b2[d];
    }
}

// ---------------------------------------------------------------------------
// Split-K f32 GEMM, 128x128 tile, BK=32, 8x8 microtile, 256 threads.
// Cp[kz][r][c] = sum_{k in kz*128..+128} A[r,k]*B[c,k]. Grid (8, 8, 8).
// ---------------------------------------------------------------------------
__global__ __launch_bounds__(256) void k_gemm_sk(
    const float* __restrict__ A, const float* __restrict__ Bw,
    float* __restrict__ Cp, int N, int K)
{
    __shared__ __align__(16) float As[32 * 132];
    __shared__ __align__(16) float Bs[32 * 132];
    int n0 = blockIdx.x * 128, m0 = blockIdx.y * 128;
    int kz = blockIdx.z;
    int tid = threadIdx.x;
    int mt = (tid & 15) * 8, nt = (tid >> 4) * 8;
    float acc[8][8] = {{0.f}};

    int kbeg = kz * 128;
    for (int k0 = kbeg; k0 < kbeg + 128; k0 += 32) {
        for (int idx = tid; idx < 128 * 32; idx += 256) {
            int kk = idx & 31, m = idx >> 5;
            As[kk * 132 + m] = A[(size_t)(m0 + m) * K + k0 + kk];
            float bvv = (n0 + m < N) ? Bw[(size_t)(n0 + m) * K + k0 + kk] : 0.f;
            Bs[kk * 132 + m] = bvv;
        }
        __syncthreads();
        #pragma unroll 4
        for (int kk = 0; kk < 32; ++kk) {
            float4 a0 = *(const float4*)&As[kk * 132 + mt];
            float4 a1 = *(const float4*)&As[kk * 132 + mt + 4];
            float4 b0 = *(const float4*)&Bs[kk * 132 + nt];
            float4 b1 = *(const float4*)&Bs[kk * 132 + nt + 4];
            float av[8] = {a0.x, a0.y, a0.z, a0.w, a1.x, a1.y, a1.z, a1.w};
            float bvr[8] = {b0.x, b0.y, b0.z, b0.w, b1.x, b1.y, b1.z, b1.w};
            #pragma unroll
            for (int i = 0; i < 8; ++i)
                #pragma unroll
                for (int j = 0; j < 8; ++j)
                    acc[i][j] = fmaf(av[i], bvr[j], acc[i][j]);
        }
        __syncthreads();
    }

    float* cpb = Cp + (size_t)kz * ((size_t)1024 * N);
    #pragma unroll
    for (int i = 0; i < 8; ++i) {
        int r = m0 + mt + i;
        #pragma unroll
        for (int j = 0; j < 8; ++j) {
            int c = n0 + nt + j;
            if (c < N) cpb[(size_t)r * N + c] = acc[i][j];
        }
    }
}

// ---------------------------------------------------------------------------
// Reduce split-K partials: C = sum Cp + bias + (res?).
// ---------------------------------------------------------------------------
__global__ __launch_bounds__(256) void k_reduce(
    const float* __restrict__ Cp, const float* __restrict__ bias,
    const float* __restrict__ res, float* __restrict__ C, int N)
{
    const int N4 = N >> 2;
    int e4 = blockIdx.x * 256 + threadIdx.x;
    if (e4 >= 1024 * N4) return;
    int r = e4 / N4;
    int c = (e4 - r * N4) << 2;
    size_t off = (size_t)r * N + c;
    const size_t slice = (size_t)1024 * N;
    float4 s = make_float4(0.f, 0.f, 0.f, 0.f);
    #pragma unroll
    for (int kz = 0; kz < 8; ++kz) {
        float4 v = *(const float4*)(Cp + kz * slice + off);
        s.x += v.x; s.y += v.y; s.z += v.z; s.w += v.w;
    }
    float4 bb = *(const float4*)(bias + c);
    s.x += bb.x; s.y += bb.y; s.z += bb.z; s.w += bb.w;
    if (res) {
        float4 rv = *(const float4*)(res + off);
        s.x += rv.x; s.y += rv.y; s.z += rv.z; s.w += rv.w;
    }
    *(float4*)(C + off) = s;
}

// ---------------------------------------------------------------------------
// Row softmax over 1000 logits -> d_out
// ---------------------------------------------------------------------------
__global__ __launch_bounds__(256) void k_softmax(
    const float* __restrict__ logits, float* __restrict__ out)
{
    int b = blockIdx.x, tid = threadIdx.x;
    __shared__ float red[8];
    float v[4];
    #pragma unroll
    for (int i = 0; i < 4; ++i) {
        int idx = tid + (i << 8);
        v[i] = (idx < 1000) ? logits[(size_t)b * 1000 + idx] : -INFINITY;
    }
    float mx = fmaxf(fmaxf(v[0], v[1]), fmaxf(v[2], v[3]));
    mx = block_max(mx, red);
    float e[4]; float s = 0.f;
    #pragma unroll
    for (int i = 0; i < 4; ++i) {
        int idx = tid + (i << 8);
        e[i] = (idx < 1000) ? expf(v[i] - mx) : 0.f;
        s += e[i];
    }
    s = block_sum(s, red);
    float inv = 1.f / s;
    #pragma unroll
    for (int i = 0; i < 4; ++i) {
        int idx = tid + (i << 8);
        if (idx < 1000) out[(size_t)b * 1000 + idx] = e[i] * inv;
    }
}

// ---------------------------------------------------------------------------
extern "C" void kernel_launch(void* const* d_in, const int* in_sizes, int n_in,
                              void* d_out, int out_size, void* d_ws, size_t ws_size,
                              hipStream_t stream)
{
    const float* x    = (const float*)d_in[0];
    const float* cls  = (const float*)d_in[1];
    const float* Wp   = (const float*)d_in[2];
    const float* ln1w = (const float*)d_in[3];
    const float* ln1b = (const float*)d_in[4];
    const float* Wq   = (const float*)d_in[5];
    const float* bq   = (const float*)d_in[6];
    const float* Wk   = (const float*)d_in[7];
    const float* bk   = (const float*)d_in[8];
    const float* Wv   = (const float*)d_in[9];
    const float* bv   = (const float*)d_in[10];
    const float* ln2w = (const float*)d_in[11];
    const float* ln2b = (const float*)d_in[12];
    const float* Wm   = (const float*)d_in[13];
    const float* bm   = (const float*)d_in[14];
    const float* Wh   = (const float*)d_in[15];
    const float* bh   = (const float*)d_in[16];
    float* out = (float*)d_out;
    (void)bk;   // q0.bk softmax-invariant

    char* ws = (char*)d_ws;
    size_t off = 0;
    auto alloc = [&](size_t nfloats) -> float* {
        float* p = (float*)(ws + off);
        off += ((nfloats * 4 + 255) & ~(size_t)255);
        return p;
    };
    float* pe     = alloc(50 * 1024);
    float* tok0c  = alloc(1024);
    float* n0g    = alloc(1024);
    float* qlw    = alloc(1024);
    float* score0 = alloc(16);
    float* kap    = alloc(16);
    float* bet    = alloc(16);
    float* Gt     = alloc(256);
    float* ut     = alloc(16);
    float* gt     = alloc(256);
    float* pwt    = alloc(50 * 16);
    float* pe2t   = alloc(50);
    float* pemean = alloc(50);
    float* pesum  = alloc(50 * 16);
    float* cg     = alloc((size_t)1024 * 1024);
    float* A0     = alloc((size_t)1024 * 1024);
    float* tok0   = alloc((size_t)1024 * 1024);
    float* n2     = alloc((size_t)1024 * 1024);
    float* t2     = alloc((size_t)1024 * 1024);
    float* logits = alloc((size_t)1024 * 1000);
    float* Cp     = alloc((size_t)8 * 1024 * 1024);

    k_pe<<<50, 256, 0, stream>>>(pe);
    k_prep_a<<<1, 256, 0, stream>>>(cls, pe, ln1w, ln1b, Wq, bq, Wk,
                                    tok0c, n0g, qlw, score0, kap, bet);
    k_prep_b<<<52, 256, 0, stream>>>(pe, Wp, qlw, pwt, pe2t, pemean, pesum,
                                     Gt, ut, gt);
    k_fused<<<256, 256, 0, stream>>>(x, pe, Wp, ln1w, ln1b,
                                     n0g, score0, kap, bet, Gt, ut, gt,
                                     pwt, pe2t, pemean, pesum, cg);
    k_av<<<dim3(16, 16), 256, 0, stream>>>(cg, Wv, bv, A0);

    k_c1<<<1024, 256, 0, stream>>>(tok0c, A0, ln2w, ln2b, tok0, n2);

    // MLP GEMM (row 0): t2 = tok0 + n2 @ Wm^T + bm
    k_gemm_sk<<<dim3(8, 8, 8), 256, 0, stream>>>(n2, Wm, Cp, 1024, 1024);
    k_reduce<<<1024, 256, 0, stream>>>(Cp, bm, tok0, t2, 1024);

    // Head GEMM: logits = t2 @ Wh^T + bh
    k_gemm_sk<<<dim3(8, 8, 8), 256, 0, stream>>>(t2, Wh, Cp, 1000, 1024);
    k_reduce<<<1000, 256, 0, stream>>>(Cp, bh, nullptr, logits, 1000);

    k_softmax<<<1024, 256, 0, stream>>>(logits, out);
}

// Round 13
// 285.363 us; speedup vs baseline: 1.2916x; 1.2916x over previous
//
#include <hip/hip_runtime.h>
#include <math.h>

// ---------------------------------------------------------------------------
// ViT forward, f32. B=1024, D=1024, H=16, DH=64, S=50, OUT=1000.
// Class-token attention collapsed to 16-dim patch algebra (rounds 10-12).
// Round-13: GEMM reverted to measured 64x64 tile (round-9) + register
// double-buffered staging (float4 global loads issued before compute phase).
// ---------------------------------------------------------------------------

#define EPS 1e-5f

__device__ __forceinline__ float warp_sum64(float v) {
    #pragma unroll
    for (int off = 32; off >= 1; off >>= 1) v += __shfl_xor(v, off, 64);
    return v;
}
__device__ __forceinline__ float warp_max64(float v) {
    #pragma unroll
    for (int off = 32; off >= 1; off >>= 1) v = fmaxf(v, __shfl_xor(v, off, 64));
    return v;
}

__device__ __forceinline__ float block_sum(float v, float* red) {
    v = warp_sum64(v);
    int lane = threadIdx.x & 63, w = threadIdx.x >> 6;
    if (lane == 0) red[w] = v;
    __syncthreads();
    int nw = blockDim.x >> 6;
    if (w == 0) {
        float x = (lane < nw) ? red[lane] : 0.f;
        x = warp_sum64(x);
        if (lane == 0) red[0] = x;
    }
    __syncthreads();
    float r = red[0];
    __syncthreads();
    return r;
}

__device__ __forceinline__ float block_max(float v, float* red) {
    v = warp_max64(v);
    int lane = threadIdx.x & 63, w = threadIdx.x >> 6;
    if (lane == 0) red[w] = v;
    __syncthreads();
    int nw = blockDim.x >> 6;
    if (w == 0) {
        float x = (lane < nw) ? red[lane] : -INFINITY;
        x = warp_max64(x);
        if (lane == 0) red[0] = x;
    }
    __syncthreads();
    float r = red[0];
    __syncthreads();
    return r;
}

// ---------------------------------------------------------------------------
// PE table
// ---------------------------------------------------------------------------
__global__ __launch_bounds__(256) void k_pe(float* __restrict__ pe) {
    int s = blockIdx.x;
    for (int d = threadIdx.x; d < 1024; d += 256) {
        int di = d & ~1;
        float freq = expf(-((float)di * (1.0f / 1024.f)) * 9.210340371976184f);
        float arg = (float)s * freq;
        pe[s * 1024 + d] = (d & 1) ? cosf(arg) : sinf(arg);
    }
}

// ---------------------------------------------------------------------------
// Prep A (1 block): tok0c=cls+pe0, LN1 -> n0; q0 = Wq n0 + bq;
// qk[d] = 32 * sum_e Wk[h][e][dl] q0[e]  (sqrt(D) temperature);
// qlw = qk*ln1w; score0[h]=qk.n0, kappa[h]=sum qlw, beta[h]=qk.lb per head.
// ---------------------------------------------------------------------------
__global__ __launch_bounds__(256) void k_prep_a(
    const float* __restrict__ cls, const float* __restrict__ pe,
    const float* __restrict__ ln1w, const float* __restrict__ ln1b,
    const float* __restrict__ Wq, const float* __restrict__ bq,
    const float* __restrict__ Wk,
    float* __restrict__ tok0c, float* __restrict__ n0g,
    float* __restrict__ qlw,
    float* __restrict__ score0, float* __restrict__ kap, float* __restrict__ bet)
{
    __shared__ float red[8];
    __shared__ float n0s[1024], q0s[1024];
    __shared__ float partA[256], partK[256], partB[256];
    int t = threadIdx.x;
    int h = t >> 4;

    float tv[4];
    #pragma unroll
    for (int i = 0; i < 4; ++i) {
        int d = t * 4 + i;
        tv[i] = cls[d] + pe[d];
        tok0c[d] = tv[i];
    }
    float sum = block_sum(tv[0] + tv[1] + tv[2] + tv[3], red);
    float mu = sum * (1.f / 1024.f);
    float d2 = 0.f;
    #pragma unroll
    for (int i = 0; i < 4; ++i) { float dv = tv[i] - mu; d2 = fmaf(dv, dv, d2); }
    float var = block_sum(d2, red) * (1.f / 1024.f);
    float rstd = rsqrtf(var + EPS);
    #pragma unroll
    for (int i = 0; i < 4; ++i) {
        int d = t * 4 + i;
        float nv = (tv[i] - mu) * rstd * ln1w[d] + ln1b[d];
        n0s[d] = nv; n0g[d] = nv;
    }
    __syncthreads();

    #pragma unroll
    for (int i = 0; i < 4; ++i) {
        int e = t * 4 + i, el = e & 63;
        const float* wr = Wq + ((size_t)h << 12) + el * 64;
        float acc = bq[e];
        for (int dd = 0; dd < 64; ++dd) acc = fmaf(wr[dd], n0s[(h << 6) + dd], acc);
        q0s[e] = acc;
    }
    __syncthreads();

    float pA = 0.f, pK = 0.f, pB = 0.f;
    #pragma unroll
    for (int i = 0; i < 4; ++i) {
        int d = t * 4 + i, dl = d & 63;
        const float* wc = Wk + ((size_t)h << 12) + dl;
        float acc = 0.f;
        for (int ee = 0; ee < 64; ++ee) acc = fmaf(wc[ee * 64], q0s[(h << 6) + ee], acc);
        acc *= 32.0f;                  // sqrt(D)=32 temperature
        float ql = acc * ln1w[d];
        qlw[d] = ql;
        pA = fmaf(acc, n0s[d], pA);
        pK += ql;
        pB = fmaf(acc, ln1b[d], pB);
    }
    partA[t] = pA; partK[t] = pK; partB[t] = pB;
    __syncthreads();
    if (t < 16) {
        float sA = 0.f, sK = 0.f, sB = 0.f;
        #pragma unroll
        for (int i = 0; i < 16; ++i) {
            sA += partA[t * 16 + i]; sK += partK[t * 16 + i]; sB += partB[t * 16 + i];
        }
        score0[t] = sA; kap[t] = sK; bet[t] = sB;
    }
}

// ---------------------------------------------------------------------------
// Prep B (52 blocks): 0..49 -> pw[s][16], pe2[s], pemean[s], pesum[s][16];
// 50 -> G=Wp^T Wp, u; 51 -> g[h][16].
// ---------------------------------------------------------------------------
__global__ __launch_bounds__(256) void k_prep_b(
    const float* __restrict__ pe, const float* __restrict__ Wp,
    const float* __restrict__ qlw,
    float* __restrict__ pwt, float* __restrict__ pe2t,
    float* __restrict__ pemean, float* __restrict__ pesum,
    float* __restrict__ Gt, float* __restrict__ ut, float* __restrict__ gt)
{
    int blk = blockIdx.x, t = threadIdx.x;
    if (blk < 50) {
        __shared__ float red[8];
        __shared__ float pwbuf[256 * 16];
        __shared__ float psbuf[256];
        int s = blk;
        float pwp[16];
        #pragma unroll
        for (int j = 0; j < 16; ++j) pwp[j] = 0.f;
        float pep = 0.f, pe2p = 0.f, psp = 0.f;
        #pragma unroll
        for (int i = 0; i < 4; ++i) {
            int d = t * 4 + i;
            float e = pe[s * 1024 + d];
            pep += e; pe2p = fmaf(e, e, pe2p); psp = fmaf(qlw[d], e, psp);
            const float* wr = Wp + (size_t)d * 16;
            #pragma unroll
            for (int j = 0; j < 16; ++j) pwp[j] = fmaf(wr[j], e, pwp[j]);
        }
        #pragma unroll
        for (int j = 0; j < 16; ++j) pwbuf[t * 16 + j] = pwp[j];
        psbuf[t] = psp;
        float pes = block_sum(pep, red);
        float pe2s = block_sum(pe2p, red);
        if (t < 16) {
            float a = 0.f;
            for (int k = 0; k < 256; ++k) a += pwbuf[k * 16 + t];
            pwt[s * 16 + t] = a;
            float b = 0.f;
            #pragma unroll
            for (int k = 0; k < 16; ++k) b += psbuf[t * 16 + k];
            pesum[s * 16 + t] = b;
        }
        if (t == 0) { pe2t[s] = pe2s; pemean[s] = pes * (1.f / 1024.f); }
    } else if (blk == 50) {
        int j = t >> 4, k = t & 15;
        float a = 0.f;
        for (int d = 0; d < 1024; ++d)
            a = fmaf(Wp[(size_t)d * 16 + j], Wp[(size_t)d * 16 + k], a);
        Gt[j * 16 + k] = a;
        if (t < 16) {
            float ua = 0.f;
            for (int d = 0; d < 1024; ++d) ua += Wp[(size_t)d * 16 + t];
            ut[t] = ua * (1.f / 1024.f);
        }
    } else {
        int h = t >> 4, j = t & 15;
        float a = 0.f;
        for (int dl = 0; dl < 64; ++dl) {
            int d = h * 64 + dl;
            a = fmaf(qlw[d], Wp[(size_t)d * 16 + j], a);
        }
        gt[h * 16 + j] = a;
    }
}

// ---------------------------------------------------------------------------
// Fused embed+attention -> context c. One wave per batch (4 waves/block).
// ---------------------------------------------------------------------------
__global__ __launch_bounds__(256) void k_fused(
    const float* __restrict__ x, const float* __restrict__ pe,
    const float* __restrict__ Wp,
    const float* __restrict__ ln1w, const float* __restrict__ ln1b,
    const float* __restrict__ n0g, const float* __restrict__ score0,
    const float* __restrict__ kap, const float* __restrict__ bet,
    const float* __restrict__ Gt, const float* __restrict__ ut,
    const float* __restrict__ gt,
    const float* __restrict__ pwt, const float* __restrict__ pe2t,
    const float* __restrict__ pemean, const float* __restrict__ pesum,
    float* __restrict__ cg)
{
    __shared__ float Gs[256], gs[256];
    __shared__ float us[16], kaps[16], bets[16], s0s[16];
    __shared__ int   prc[50];
    __shared__ float n0s[1024], lws[1024], lbs[1024];
    __shared__ float xs[4][800];
    __shared__ float mus[4][52], rss[4][52];
    __shared__ float sc[4][16][52];
    __shared__ float wpat[4][16][17];
    __shared__ float wmus[4][16];

    int t = threadIdx.x, w = t >> 6, lane = t & 63;
    int b = blockIdx.x * 4 + w;

    Gs[t] = Gt[t];
    gs[t] = gt[t];
    if (t < 16) { us[t] = ut[t]; kaps[t] = kap[t]; bets[t] = bet[t]; s0s[t] = score0[t]; }
    if (t >= 1 && t < 50) prc[t] = ((t - 1) / 7) * 112 + ((t - 1) % 7) * 4;
    #pragma unroll
    for (int i = 0; i < 4; ++i) {
        int d = t + (i << 8);
        n0s[d] = n0g[d]; lws[d] = ln1w[d]; lbs[d] = ln1b[d];
    }
    for (int i = lane; i < 784; i += 64) xs[w][i] = x[b * 784 + i];
    __syncthreads();

    // ---- Phase A: per-row stats + scores (lane = s) ----
    {
        int s = lane;
        if (s >= 1 && s < 50) {
            float p[16];
            int off = prc[s];
            #pragma unroll
            for (int j = 0; j < 16; ++j) p[j] = xs[w][off + (j >> 2) * 28 + (j & 3)];
            float mu = pemean[s];
            #pragma unroll
            for (int j = 0; j < 16; ++j) mu = fmaf(us[j], p[j], mu);
            float ssq = pe2t[s];
            #pragma unroll
            for (int j = 0; j < 16; ++j) {
                float gpj = 0.f;
                #pragma unroll
                for (int k = 0; k < 16; ++k) gpj = fmaf(Gs[j * 16 + k], p[k], gpj);
                ssq = fmaf(p[j], gpj, ssq);
            }
            const float* pwr = pwt + s * 16;
            #pragma unroll
            for (int j = 0; j < 16; ++j) ssq = fmaf(2.f * p[j], pwr[j], ssq);
            float var = ssq * (1.f / 1024.f) - mu * mu;
            float rsv = rsqrtf(var + EPS);
            mus[w][s] = mu; rss[w][s] = rsv;
            const float* pss = pesum + s * 16;
            #pragma unroll
            for (int h = 0; h < 16; ++h) {
                float gp = 0.f;
                #pragma unroll
                for (int j = 0; j < 16; ++j) gp = fmaf(gs[h * 16 + j], p[j], gp);
                sc[w][h][s] = rsv * (gp + pss[h] - mu * kaps[h]) + bets[h];
            }
        } else if (s == 50) {
            #pragma unroll
            for (int h = 0; h < 16; ++h) sc[w][h][0] = s0s[h];
        }
    }
    __syncthreads();

    // ---- Phase B: softmax over 50 per head (4 lanes per head) ----
    int h = lane & 15, q = lane >> 4;
    {
        int sb = q * 13, se = (sb + 13 < 50) ? sb + 13 : 50;
        float mx = -1e30f;
        for (int ss = sb; ss < se; ++ss) mx = fmaxf(mx, sc[w][h][ss]);
        mx = fmaxf(mx, __shfl_xor(mx, 16, 64));
        mx = fmaxf(mx, __shfl_xor(mx, 32, 64));
        float sm = 0.f;
        for (int ss = sb; ss < se; ++ss) {
            float e = expf(sc[w][h][ss] - mx);
            sc[w][h][ss] = e;
            sm += e;
        }
        sm += __shfl_xor(sm, 16, 64);
        sm += __shfl_xor(sm, 32, 64);
        float inv = 1.f / sm;
        for (int ss = sb; ss < se; ++ss) sc[w][h][ss] *= inv;
    }
    __syncthreads();

    // ---- Phase C: wpatch_h[16], wmu_h ----
    {
        int sb = q * 13, se = (sb + 13 < 50) ? sb + 13 : 50;
        int s0c = (q == 0) ? 1 : sb;
        float acc[16], amu = 0.f;
        #pragma unroll
        for (int j = 0; j < 16; ++j) acc[j] = 0.f;
        for (int ss = s0c; ss < se; ++ss) {
            float wgt = sc[w][h][ss] * rss[w][ss];
            int off = prc[ss];
            #pragma unroll
            for (int j = 0; j < 16; ++j)
                acc[j] = fmaf(wgt, xs[w][off + (j >> 2) * 28 + (j & 3)], acc[j]);
            amu = fmaf(wgt, mus[w][ss], amu);
        }
        #pragma unroll
        for (int j = 0; j < 16; ++j) {
            acc[j] += __shfl_xor(acc[j], 16, 64);
            acc[j] += __shfl_xor(acc[j], 32, 64);
        }
        amu += __shfl_xor(amu, 16, 64);
        amu += __shfl_xor(amu, 32, 64);
        if (q == 0) {
            #pragma unroll
            for (int j = 0; j < 16; ++j) wpat[w][h][j] = acc[j];
            wmus[w][h] = amu;
        }
    }
    __syncthreads();

    // ---- Phase D: context c, coalesced: d = i*64 + lane, head = i ----
    {
        float wpe[16];
        #pragma unroll
        for (int i = 0; i < 16; ++i) wpe[i] = 0.f;
        for (int ss = 1; ss < 50; ++ss) {
            float rsv = rss[w][ss];
            const float* per = pe + ss * 1024 + lane;
            #pragma unroll
            for (int i = 0; i < 16; ++i) {
                float wgt = sc[w][i][ss] * rsv;
                wpe[i] = fmaf(wgt, per[i * 64], wpe[i]);
            }
        }
        #pragma unroll
        for (int i = 0; i < 16; ++i) {
            int d = i * 64 + lane;
            float p0 = sc[w][i][0];
            const float4* wr = (const float4*)(Wp + (size_t)d * 16);
            float4 wa = wr[0], wb = wr[1], wc = wr[2], wd = wr[3];
            const float* wp_h = wpat[w][i];
            float wp_ = 0.f;
            wp_ = fmaf(wa.x, wp_h[0], wp_);  wp_ = fmaf(wa.y, wp_h[1], wp_);
            wp_ = fmaf(wa.z, wp_h[2], wp_);  wp_ = fmaf(wa.w, wp_h[3], wp_);
            wp_ = fmaf(wb.x, wp_h[4], wp_);  wp_ = fmaf(wb.y, wp_h[5], wp_);
            wp_ = fmaf(wb.z, wp_h[6], wp_);  wp_ = fmaf(wb.w, wp_h[7], wp_);
            wp_ = fmaf(wc.x, wp_h[8], wp_);  wp_ = fmaf(wc.y, wp_h[9], wp_);
            wp_ = fmaf(wc.z, wp_h[10], wp_); wp_ = fmaf(wc.w, wp_h[11], wp_);
            wp_ = fmaf(wd.x, wp_h[12], wp_); wp_ = fmaf(wd.y, wp_h[13], wp_);
            wp_ = fmaf(wd.z, wp_h[14], wp_); wp_ = fmaf(wd.w, wp_h[15], wp_);
            float ci = p0 * n0s[d] + lws[d] * (wp_ + wpe[i] - wmus[w][i])
                     + lbs[d] * (1.f - p0);
            cg[(size_t)b * 1024 + d] = ci;
        }
    }
}

// ---------------------------------------------------------------------------
// k_av: A0[b, h*64+e] = sum_d Wv[h][e][d] * c[b, h*64+d] + bv[h*64+e].
// ---------------------------------------------------------------------------
__global__ __launch_bounds__(256) void k_av(
    const float* __restrict__ cg, const float* __restrict__ Wv,
    const float* __restrict__ bv, float* __restrict__ A0)
{
    __shared__ __align__(16) float wvt[64 * 68];   // [d][e]
    __shared__ __align__(16) float cst[64 * 68];   // [d][bb]
    int b0 = blockIdx.x * 64, hh = blockIdx.y;
    int tid = threadIdx.x;

    for (int idx = tid; idx < 4096; idx += 256) {
        int row = idx >> 6, col = idx & 63;
        wvt[col * 68 + row] = Wv[((size_t)hh << 12) + idx];
        cst[col * 68 + row] = cg[(size_t)(b0 + row) * 1024 + (hh << 6) + col];
    }
    __syncthreads();

    int bt = (tid & 15) * 4, et = (tid >> 4) * 4;
    float acc[4][4] = {{0.f}};
    #pragma unroll 8
    for (int d = 0; d < 64; ++d) {
        float4 cv = *(const float4*)&cst[d * 68 + bt];
        float4 wv4 = *(const float4*)&wvt[d * 68 + et];
        acc[0][0] = fmaf(cv.x, wv4.x, acc[0][0]);
        acc[0][1] = fmaf(cv.x, wv4.y, acc[0][1]);
        acc[0][2] = fmaf(cv.x, wv4.z, acc[0][2]);
        acc[0][3] = fmaf(cv.x, wv4.w, acc[0][3]);
        acc[1][0] = fmaf(cv.y, wv4.x, acc[1][0]);
        acc[1][1] = fmaf(cv.y, wv4.y, acc[1][1]);
        acc[1][2] = fmaf(cv.y, wv4.z, acc[1][2]);
        acc[1][3] = fmaf(cv.y, wv4.w, acc[1][3]);
        acc[2][0] = fmaf(cv.z, wv4.x, acc[2][0]);
        acc[2][1] = fmaf(cv.z, wv4.y, acc[2][1]);
        acc[2][2] = fmaf(cv.z, wv4.z, acc[2][2]);
        acc[2][3] = fmaf(cv.z, wv4.w, acc[2][3]);
        acc[3][0] = fmaf(cv.w, wv4.x, acc[3][0]);
        acc[3][1] = fmaf(cv.w, wv4.y, acc[3][1]);
        acc[3][2] = fmaf(cv.w, wv4.z, acc[3][2]);
        acc[3][3] = fmaf(cv.w, wv4.w, acc[3][3]);
    }
    #pragma unroll
    for (int i = 0; i < 4; ++i) {
        int b = b0 + bt + i;
        #pragma unroll
        for (int j = 0; j < 4; ++j) {
            int e = (hh << 6) + et + j;
            A0[(size_t)b * 1024 + e] = acc[i][j] + bv[e];
        }
    }
}

// ---------------------------------------------------------------------------
// C1: t = tok0c + A0; tok0[b]=t; LN2 -> n2. One block per b.
// ---------------------------------------------------------------------------
__global__ __launch_bounds__(256) void k_c1(
    const float* __restrict__ tok0c, const float* __restrict__ A0,
    const float* __restrict__ w2, const float* __restrict__ b2,
    float* __restrict__ tok0, float* __restrict__ n2)
{
    int b = blockIdx.x, tid = threadIdx.x;
    __shared__ float red[8];
    float t[4];
    #pragma unroll
    for (int i = 0; i < 4; ++i) {
        int d = tid + (i << 8);
        t[i] = tok0c[d] + A0[(size_t)b * 1024 + d];
    }
    float sum = block_sum(t[0] + t[1] + t[2] + t[3], red);
    float mu = sum * (1.f / 1024.f);
    float d2 = 0.f;
    #pragma unroll
    for (int i = 0; i < 4; ++i) { float dv = t[i] - mu; d2 = fmaf(dv, dv, d2); }
    float var = block_sum(d2, red) * (1.f / 1024.f);
    float rstd = rsqrtf(var + EPS);
    #pragma unroll
    for (int i = 0; i < 4; ++i) {
        int d = tid + (i << 8);
        tok0[(size_t)b * 1024 + d] = t[i];
        n2[(size_t)b * 1024 + d] = (t[i] - mu) * rstd * w2[d] + b2[d];
    }
}

// ---------------------------------------------------------------------------
// Split-K f32 GEMM, 64x64 tile (round-9 measured structure), BK=32, 4x4
// microtile, register double-buffered staging: next k-tile's global loads
// are issued BEFORE the compute phase so VMEM latency hides under FMAs.
// Cp[kz][r][c] = sum_{k in kz*128..+128} A[r,k]*B[c,k]. Grid (16, 16, 8).
// ---------------------------------------------------------------------------
__global__ __launch_bounds__(256) void k_gemm_sk(
    const float* __restrict__ A, const float* __restrict__ Bw,
    float* __restrict__ Cp, int N, int K)
{
    __shared__ __align__(16) float As[32 * 68];
    __shared__ __align__(16) float Bs[32 * 68];
    int n0 = blockIdx.x * 64, m0 = blockIdx.y * 64;
    int kz = blockIdx.z;
    int tid = threadIdx.x;
    int mt = (tid & 15) * 4, nt = (tid >> 4) * 4;

    // staging: 512 float4 units (64 rows x 8 f4-cols); thread owns tid, tid+256
    const int am0 = tid >> 3,        ac0 = (tid & 7) * 4;         // row, col
    const int am1 = (tid + 256) >> 3, ac1 = ((tid + 256) & 7) * 4;
    const bool bv0 = (n0 + am0) < N, bv1 = (n0 + am1) < N;
    const float4 z4 = make_float4(0.f, 0.f, 0.f, 0.f);

    float acc[4][4] = {{0.f}};
    float4 ra0, ra1, rb0, rb1;

    int kbeg = kz * 128;
    ra0 = *(const float4*)(A + (size_t)(m0 + am0) * K + kbeg + ac0);
    ra1 = *(const float4*)(A + (size_t)(m0 + am1) * K + kbeg + ac1);
    rb0 = bv0 ? *(const float4*)(Bw + (size_t)(n0 + am0) * K + kbeg + ac0) : z4;
    rb1 = bv1 ? *(const float4*)(Bw + (size_t)(n0 + am1) * K + kbeg + ac1) : z4;

    #pragma unroll
    for (int step = 0; step < 4; ++step) {
        // regs -> LDS (transposed to [kk][m], stride 68)
        As[(ac0 + 0) * 68 + am0] = ra0.x;
        As[(ac0 + 1) * 68 + am0] = ra0.y;
        As[(ac0 + 2) * 68 + am0] = ra0.z;
        As[(ac0 + 3) * 68 + am0] = ra0.w;
        As[(ac1 + 0) * 68 + am1] = ra1.x;
        As[(ac1 + 1) * 68 + am1] = ra1.y;
        As[(ac1 + 2) * 68 + am1] = ra1.z;
        As[(ac1 + 3) * 68 + am1] = ra1.w;
        Bs[(ac0 + 0) * 68 + am0] = rb0.x;
        Bs[(ac0 + 1) * 68 + am0] = rb0.y;
        Bs[(ac0 + 2) * 68 + am0] = rb0.z;
        Bs[(ac0 + 3) * 68 + am0] = rb0.w;
        Bs[(ac1 + 0) * 68 + am1] = rb1.x;
        Bs[(ac1 + 1) * 68 + am1] = rb1.y;
        Bs[(ac1 + 2) * 68 + am1] = rb1.z;
        Bs[(ac1 + 3) * 68 + am1] = rb1.w;
        __syncthreads();

        if (step < 3) {   // issue next tile's loads; latency hides under FMAs
            int k0 = kbeg + (step + 1) * 32;
            ra0 = *(const float4*)(A + (size_t)(m0 + am0) * K + k0 + ac0);
            ra1 = *(const float4*)(A + (size_t)(m0 + am1) * K + k0 + ac1);
            rb0 = bv0 ? *(const float4*)(Bw + (size_t)(n0 + am0) * K + k0 + ac0) : z4;
            rb1 = bv1 ? *(const float4*)(Bw + (size_t)(n0 + am1) * K + k0 + ac1) : z4;
        }

        #pragma unroll 8
        for (int kk = 0; kk < 32; ++kk) {
            float4 av = *(const float4*)&As[kk * 68 + mt];
            float4 bv4 = *(const float4*)&Bs[kk * 68 + nt];
            acc[0][0] = fmaf(av.x, bv4.x, acc[0][0]);
            acc[0][1] = fmaf(av.x, bv4.y, acc[0][1]);
            acc[0][2] = fmaf(av.x, bv4.z, acc[0][2]);
            acc[0][3] = fmaf(av.x, bv4.w, acc[0][3]);
            acc[1][0] = fmaf(av.y, bv4.x, acc[1][0]);
            acc[1][1] = fmaf(av.y, bv4.y, acc[1][1]);
            acc[1][2] = fmaf(av.y, bv4.z, acc[1][2]);
            acc[1][3] = fmaf(av.y, bv4.w, acc[1][3]);
            acc[2][0] = fmaf(av.z, bv4.x, acc[2][0]);
            acc[2][1] = fmaf(av.z, bv4.y, acc[2][1]);
            acc[2][2] = fmaf(av.z, bv4.z, acc[2][2]);
            acc[2][3] = fmaf(av.z, bv4.w, acc[2][3]);
            acc[3][0] = fmaf(av.w, bv4.x, acc[3][0]);
            acc[3][1] = fmaf(av.w, bv4.y, acc[3][1]);
            acc[3][2] = fmaf(av.w, bv4.z, acc[3][2]);
            acc[3][3] = fmaf(av.w, bv4.w, acc[3][3]);
        }
        __syncthreads();
    }

    float* cpb = Cp + (size_t)kz * ((size_t)1024 * N);
    #pragma unroll
    for (int i = 0; i < 4; ++i) {
        int r = m0 + mt + i;
        #pragma unroll
        for (int j = 0; j < 4; ++j) {
            int c = n0 + nt + j;
            if (c < N) cpb[(size_t)r * N + c] = acc[i][j];
        }
    }
}

// ---------------------------------------------------------------------------
// Reduce split-K partials: C = sum Cp + bias + (res?).
// ---------------------------------------------------------------------------
__global__ __launch_bounds__(256) void k_reduce(
    const float* __restrict__ Cp, const float* __restrict__ bias,
    const float* __restrict__ res, float* __restrict__ C, int N)
{
    const int N4 = N >> 2;
    int e4 = blockIdx.x * 256 + threadIdx.x;
    if (e4 >= 1024 * N4) return;
    int r = e4 / N4;
    int c = (e4 - r * N4) << 2;
    size_t off = (size_t)r * N + c;
    const size_t slice = (size_t)1024 * N;
    float4 s = make_float4(0.f, 0.f, 0.f, 0.f);
    #pragma unroll
    for (int kz = 0; kz < 8; ++kz) {
        float4 v = *(const float4*)(Cp + kz * slice + off);
        s.x += v.x; s.y += v.y; s.z += v.z; s.w += v.w;
    }
    float4 bb = *(const float4*)(bias + c);
    s.x += bb.x; s.y += bb.y; s.z += bb.z; s.w += bb.w;
    if (res) {
        float4 rv = *(const float4*)(res + off);
        s.x += rv.x; s.y += rv.y; s.z += rv.z; s.w += rv.w;
    }
    *(float4*)(C + off) = s;
}

// ---------------------------------------------------------------------------
// Row softmax over 1000 logits -> d_out
// ---------------------------------------------------------------------------
__global__ __launch_bounds__(256) void k_softmax(
    const float* __restrict__ logits, float* __restrict__ out)
{
    int b = blockIdx.x, tid = threadIdx.x;
    __shared__ float red[8];
    float v[4];
    #pragma unroll
    for (int i = 0; i < 4; ++i) {
        int idx = tid + (i << 8);
        v[i] = (idx < 1000) ? logits[(size_t)b * 1000 + idx] : -INFINITY;
    }
    float mx = fmaxf(fmaxf(v[0], v[1]), fmaxf(v[2], v[3]));
    mx = block_max(mx, red);
    float e[4]; float s = 0.f;
    #pragma unroll
    for (int i = 0; i < 4; ++i) {
        int idx = tid + (i << 8);
        e[i] = (idx < 1000) ? expf(v[i] - mx) : 0.f;
        s += e[i];
    }
    s = block_sum(s, red);
    float inv = 1.f / s;
    #pragma unroll
    for (int i = 0; i < 4; ++i) {
        int idx = tid + (i << 8);
        if (idx < 1000) out[(size_t)b * 1000 + idx] = e[i] * inv;
    }
}

// ---------------------------------------------------------------------------
extern "C" void kernel_launch(void* const* d_in, const int* in_sizes, int n_in,
                              void* d_out, int out_size, void* d_ws, size_t ws_size,
                              hipStream_t stream)
{
    const float* x    = (const float*)d_in[0];
    const float* cls  = (const float*)d_in[1];
    const float* Wp   = (const float*)d_in[2];
    const float* ln1w = (const float*)d_in[3];
    const float* ln1b = (const float*)d_in[4];
    const float* Wq   = (const float*)d_in[5];
    const float* bq   = (const float*)d_in[6];
    const float* Wk   = (const float*)d_in[7];
    const float* bk   = (const float*)d_in[8];
    const float* Wv   = (const float*)d_in[9];
    const float* bv   = (const float*)d_in[10];
    const float* ln2w = (const float*)d_in[11];
    const float* ln2b = (const float*)d_in[12];
    const float* Wm   = (const float*)d_in[13];
    const float* bm   = (const float*)d_in[14];
    const float* Wh   = (const float*)d_in[15];
    const float* bh   = (const float*)d_in[16];
    float* out = (float*)d_out;
    (void)bk;   // q0.bk softmax-invariant

    char* ws = (char*)d_ws;
    size_t off = 0;
    auto alloc = [&](size_t nfloats) -> float* {
        float* p = (float*)(ws + off);
        off += ((nfloats * 4 + 255) & ~(size_t)255);
        return p;
    };
    float* pe     = alloc(50 * 1024);
    float* tok0c  = alloc(1024);
    float* n0g    = alloc(1024);
    float* qlw    = alloc(1024);
    float* score0 = alloc(16);
    float* kap    = alloc(16);
    float* bet    = alloc(16);
    float* Gt     = alloc(256);
    float* ut     = alloc(16);
    float* gt     = alloc(256);
    float* pwt    = alloc(50 * 16);
    float* pe2t   = alloc(50);
    float* pemean = alloc(50);
    float* pesum  = alloc(50 * 16);
    float* cg     = alloc((size_t)1024 * 1024);
    float* A0     = alloc((size_t)1024 * 1024);
    float* tok0   = alloc((size_t)1024 * 1024);
    float* n2     = alloc((size_t)1024 * 1024);
    float* t2     = alloc((size_t)1024 * 1024);
    float* logits = alloc((size_t)1024 * 1000);
    float* Cp     = alloc((size_t)8 * 1024 * 1024);

    k_pe<<<50, 256, 0, stream>>>(pe);
    k_prep_a<<<1, 256, 0, stream>>>(cls, pe, ln1w, ln1b, Wq, bq, Wk,
                                    tok0c, n0g, qlw, score0, kap, bet);
    k_prep_b<<<52, 256, 0, stream>>>(pe, Wp, qlw, pwt, pe2t, pemean, pesum,
                                     Gt, ut, gt);
    k_fused<<<256, 256, 0, stream>>>(x, pe, Wp, ln1w, ln1b,
                                     n0g, score0, kap, bet, Gt, ut, gt,
                                     pwt, pe2t, pemean, pesum, cg);
    k_av<<<dim3(16, 16), 256, 0, stream>>>(cg, Wv, bv, A0);

    k_c1<<<1024, 256, 0, stream>>>(tok0c, A0, ln2w, ln2b, tok0, n2);

    // MLP GEMM (row 0): t2 = tok0 + n2 @ Wm^T + bm
    k_gemm_sk<<<dim3(16, 16, 8), 256, 0, stream>>>(n2, Wm, Cp, 1024, 1024);
    k_reduce<<<1024, 256, 0, stream>>>(Cp, bm, tok0, t2, 1024);

    // Head GEMM: logits = t2 @ Wh^T + bh
    k_gemm_sk<<<dim3(16, 16, 8), 256, 0, stream>>>(t2, Wh, Cp, 1000, 1024);
    k_reduce<<<1000, 256, 0, stream>>>(Cp, bh, nullptr, logits, 1000);

    k_softmax<<<1024, 256, 0, stream>>>(logits, out);
}